// Round 2
// baseline (818.764 us; speedup 1.0000x reference)
//
#include <hip/hip_runtime.h>

typedef unsigned short u16;
typedef unsigned int   u32;
typedef __attribute__((ext_vector_type(8))) short short8;
typedef __attribute__((ext_vector_type(4))) float f32x4;
typedef __attribute__((ext_vector_type(4))) u16  u16x4;

#define DI __device__ __forceinline__

DI float b2f(u16 v){ return __builtin_bit_cast(float, (u32)v << 16); }
DI u16 f2b(float f){ u32 u = __builtin_bit_cast(u32, f); return (u16)((u + 0x7fffu + ((u >> 16) & 1u)) >> 16); }
DI float lrelu(float v){ return v > 0.f ? v : 0.01f * v; }

// ---------------- f32 -> bf16 conversion (inputs are float32 — proven R3) --
__global__ __launch_bounds__(256)
void cvt_bf16(const float* __restrict__ in, u16* __restrict__ out, int n4)
{
  int i = blockIdx.x*256 + threadIdx.x;
  if (i >= n4) return;
  float4 v = ((const float4*)in)[i];
  u16x4 o; o[0]=f2b(v.x); o[1]=f2b(v.y); o[2]=f2b(v.z); o[3]=f2b(v.w);
  *(u16x4*)(out + (size_t)i*4) = o;
}

// ---------------- GEMM (NT): Y[M,N] = A[M,K] * W[N,K]^T, f32 out -----------
template<int BM, int BN, int WROWS, int WCOLS, int RT, int CT>
__global__ __launch_bounds__(WROWS*WCOLS*64)
void gemm_nt(const u16* __restrict__ A, const u16* __restrict__ W,
             float* __restrict__ Y, int M, int N, int K)
{
  constexpr int NT  = WROWS*WCOLS*64;
  constexpr int ALD = (BM*4)/NT;
  constexpr int BLD = (BN*4)/NT;
  __shared__ __align__(16) u16 As[BM*32];
  __shared__ __align__(16) u16 Bs[BN*32];
  const int tid  = threadIdx.x;
  const int wave = tid >> 6, lane = tid & 63;
  const int wr = wave / WCOLS, wc = wave % WCOLS;
  const int lrow = lane & 15, kg = lane >> 4;
  const int m0 = blockIdx.x * BM, n0 = blockIdx.y * BN;
  f32x4 acc[RT][CT] = {};
  for (int k0 = 0; k0 < K; k0 += 32) {
    uint4 av[ALD], bv[BLD];
#pragma unroll
    for (int i = 0; i < ALD; i++){ int x = tid + i*NT; av[i] = *(const uint4*)(A + (size_t)(m0 + (x>>2))*K + k0 + (x&3)*8); }
#pragma unroll
    for (int i = 0; i < BLD; i++){ int x = tid + i*NT; bv[i] = *(const uint4*)(W + (size_t)(n0 + (x>>2))*K + k0 + (x&3)*8); }
    __syncthreads();
#pragma unroll
    for (int i = 0; i < ALD; i++){ *(uint4*)(As + (tid + i*NT)*8) = av[i]; }
#pragma unroll
    for (int i = 0; i < BLD; i++){ *(uint4*)(Bs + (tid + i*NT)*8) = bv[i]; }
    __syncthreads();
    short8 af[RT], bfr[CT];
#pragma unroll
    for (int r = 0; r < RT; r++) af[r]  = *(const short8*)(As + ((wr*RT + r)*16 + lrow)*32 + kg*8);
#pragma unroll
    for (int c = 0; c < CT; c++) bfr[c] = *(const short8*)(Bs + ((wc*CT + c)*16 + lrow)*32 + kg*8);
#pragma unroll
    for (int r = 0; r < RT; r++)
#pragma unroll
      for (int c = 0; c < CT; c++)
        acc[r][c] = __builtin_amdgcn_mfma_f32_16x16x32_bf16(af[r], bfr[c], acc[r][c], 0, 0, 0);
  }
  // C/D: col=lane&15, row=(lane>>4)*4+i  [m89/m91]
#pragma unroll
  for (int r = 0; r < RT; r++)
#pragma unroll
    for (int c = 0; c < CT; c++)
#pragma unroll
      for (int i = 0; i < 4; i++){
        int m = m0 + (wr*RT + r)*16 + kg*4 + i;
        int n = n0 + (wc*CT + c)*16 + lrow;
        Y[(size_t)m*N + n] = acc[r][c][i];
      }
}

// ---------------- BatchNorm (training-mode, batch stats), Y f32 ------------
__global__ __launch_bounds__(256)
void bn_partial(const float* __restrict__ Y, float* __restrict__ part, int N, int rowsPer)
{
  const int tx = threadIdx.x & 63, ty = threadIdx.x >> 6;
  const int n  = blockIdx.x*64 + tx;
  const int m0 = blockIdx.y * rowsPer;
  float s = 0.f, s2 = 0.f;
  for (int m = m0 + ty; m < m0 + rowsPer; m += 4){ float v = Y[(size_t)m*N + n]; s += v; s2 += v*v; }
  __shared__ float ls[4][64], ls2[4][64];
  ls[ty][tx] = s; ls2[ty][tx] = s2;
  __syncthreads();
  if (ty == 0){
    s  = ls[0][tx]+ls[1][tx]+ls[2][tx]+ls[3][tx];
    s2 = ls2[0][tx]+ls2[1][tx]+ls2[2][tx]+ls2[3][tx];
    part[(size_t)(blockIdx.y*2+0)*N + n] = s;
    part[(size_t)(blockIdx.y*2+1)*N + n] = s2;
  }
}

__global__ __launch_bounds__(256)
void bn_finalize(const float* __restrict__ part, const float* __restrict__ g,
                 const float* __restrict__ be, float* __restrict__ ss, int N, int M, int split)
{
  int n = blockIdx.x*256 + threadIdx.x;
  if (n >= N) return;
  float s = 0.f, s2 = 0.f;
  for (int i = 0; i < split; i++){ s += part[(size_t)(i*2+0)*N + n]; s2 += part[(size_t)(i*2+1)*N + n]; }
  float inv  = 1.f / (float)M;
  float mean = s * inv;
  float var  = fmaxf(s2*inv - mean*mean, 0.f);
  float sc   = g[n] * rsqrtf(var + 1e-5f);
  ss[n]     = sc;
  ss[N + n] = be[n] - mean*sc;
}

__global__ __launch_bounds__(256)
void bn_apply(const float* __restrict__ Y, const float* __restrict__ ss,
              u16* __restrict__ H, int total4, int N)
{
  int i = blockIdx.x*256 + threadIdx.x;
  if (i >= total4) return;
  float4 v = ((const float4*)Y)[i];
  int nb = (i*4) & (N-1);
  u16x4 o;
  o[0] = f2b(lrelu(v.x*ss[nb+0] + ss[N+nb+0]));
  o[1] = f2b(lrelu(v.y*ss[nb+1] + ss[N+nb+1]));
  o[2] = f2b(lrelu(v.z*ss[nb+2] + ss[N+nb+2]));
  o[3] = f2b(lrelu(v.w*ss[nb+3] + ss[N+nb+3]));
  *(u16x4*)(H + (size_t)i*4) = o;
}

// BN apply layer-4 + per-sample transpose: Xt[b][n][c] = lrelu(bn(h4))[b][c*64+n]
__global__ __launch_bounds__(256)
void bn_apply4_t(const float* __restrict__ Y, const float* __restrict__ ss, u16* __restrict__ Xt)
{
  const int b = blockIdx.x, tid = threadIdx.x;
  __shared__ u16 t[64*65];
  for (int j = tid; j < 4096; j += 256){
    float v = Y[(size_t)b*4096 + j];
    v = lrelu(v*ss[j] + ss[4096 + j]);
    int c = j >> 6, n = j & 63;
    t[c*65 + n] = f2b(v);
  }
  __syncthreads();
  for (int e = tid; e < 4096; e += 256){
    int n = e >> 6, c = e & 63;
    Xt[(size_t)b*4096 + n*64 + c] = t[c*65 + n];
  }
}

// ---------------- conv weight repack: wr[o][k*C+c] = w[o][c*3+k], f32 in ---
__global__ __launch_bounds__(256)
void repack_w(const float* __restrict__ w, u16* __restrict__ wr, int O, int C, int lgC)
{
  int e = blockIdx.x*256 + threadIdx.x;
  int R = 3*C;
  if (e >= O*R) return;
  int o = e / R; int r = e - o*R;
  int k = r >> lgC; int c = r & (C-1);
  wr[e] = f2b(w[(size_t)o*R + c*3 + k]);
}

// ---------------- tree-conv + TreeLayerNorm + LeakyReLU --------------------
// Xin: per-sample base = Xin + b*inStride, node-major (64, C) bf16.
// non-LAST out: per-sample base = Xout + b*outStride, node-major (64, O) bf16.
// LAST: Outf + b*O*64, (O, 64) f32.
// NOTE on aliasing: each block stages its ENTIRE input into LDS before writing
// any output, and reads/writes only sample b's regions — so input and output
// slices for the SAME sample may overlap in memory (used for the final conv,
// whose input lives inside sample b's own slice of d_out).
template<int C, int O, bool LAST>
__global__ __launch_bounds__(512)
void conv_norm(const u16* __restrict__ Xin, long inStride,
               const u16* __restrict__ Wr,
               const float* __restrict__ cb, const int* __restrict__ gidx,
               u16* __restrict__ Xout, long outStride, float* __restrict__ Outf)
{
  constexpr int R   = 3*C;
  constexpr int CSI = C + 8;
  constexpr int RT  = O/128;
  constexpr int LGC = (C==64)?6:((C==128)?7:8);
  __shared__ __align__(16) u16 xs[65*CSI];
  __shared__ int idxs[192];
  __shared__ float red[16];
  const int b = blockIdx.x, tid = threadIdx.x;
  const int wave = tid >> 6, lane = tid & 63;
  const int lrow = lane & 15, kg = lane >> 4;

  const u16* xg = Xin + (size_t)b*inStride;
  for (int e = tid; e < 64*(C/8); e += 512){
    int row = e/(C/8), t = e%(C/8);
    *(uint4*)(xs + row*CSI + t*8) = *(const uint4*)(xg + row*C + t*8);
  }
  for (int e = tid; e < C/8; e += 512){ uint4 z = {0,0,0,0}; *(uint4*)(xs + 64*CSI + e*8) = z; }
  if (tid < 189){ int v = gidx[b*189 + tid]; idxs[tid] = v & 63; }
  __syncthreads();

  int jt[4][3];
#pragma unroll
  for (int ct = 0; ct < 4; ct++){
    int n = ct*16 + lrow;
#pragma unroll
    for (int k = 0; k < 3; k++) jt[ct][k] = (n == 0) ? 64 : idxs[3*(n-1) + k];
  }

  f32x4 acc[RT][4] = {};
  for (int kb = 0; kb < R; kb += 32){
    const int k  = kb >> LGC;            // wave-uniform tap
    const int c0 = (kb & (C-1)) + kg*8;
    short8 bfr[4];
#pragma unroll
    for (int ct = 0; ct < 4; ct++) bfr[ct] = *(const short8*)(xs + jt[ct][k]*CSI + c0);
    short8 af[RT];
#pragma unroll
    for (int r = 0; r < RT; r++) af[r] = *(const short8*)(Wr + (size_t)((wave + 8*r)*16 + lrow)*R + kb + kg*8);
#pragma unroll
    for (int r = 0; r < RT; r++)
#pragma unroll
      for (int ct = 0; ct < 4; ct++)
        acc[r][ct] = __builtin_amdgcn_mfma_f32_16x16x32_bf16(af[r], bfr[ct], acc[r][ct], 0, 0, 0);
  }

  // bias (skip null column 0) + per-sample stats over (O x 64)
  float s = 0.f, s2 = 0.f;
#pragma unroll
  for (int r = 0; r < RT; r++)
#pragma unroll
    for (int i = 0; i < 4; i++){
      int o = (wave + 8*r)*16 + kg*4 + i;
      float bias = cb[o];
#pragma unroll
      for (int ct = 0; ct < 4; ct++){
        int n = ct*16 + lrow;
        float v = acc[r][ct][i];
        if (n != 0) v += bias;
        acc[r][ct][i] = v;
        s += v; s2 += v*v;
      }
    }
#pragma unroll
  for (int off = 32; off > 0; off >>= 1){ s += __shfl_down(s, off); s2 += __shfl_down(s2, off); }
  if (lane == 0){ red[wave] = s; red[8 + wave] = s2; }
  __syncthreads();
  if (tid == 0){
    float S = 0.f, S2 = 0.f;
    for (int w = 0; w < 8; w++){ S += red[w]; S2 += red[8 + w]; }
    const float NV = (float)(O*64);
    float mean = S / NV;
    float var  = fmaxf(S2/NV - mean*mean, 0.f) * (NV/(NV-1.f));  // torch.std ddof=1
    float sc   = 1.f / (sqrtf(var) + 1e-5f);
    red[0] = mean; red[1] = sc;
  }
  __syncthreads();
  const float mean = red[0], sc = red[1];

  if constexpr (LAST) {
#pragma unroll
    for (int r = 0; r < RT; r++)
#pragma unroll
      for (int ct = 0; ct < 4; ct++)
#pragma unroll
        for (int i = 0; i < 4; i++){
          int o = (wave + 8*r)*16 + kg*4 + i;
          int n = ct*16 + lrow;
          Outf[(size_t)b*(O*64) + o*64 + n] = lrelu((acc[r][ct][i] - mean)*sc);  // f32 output
        }
  } else {
#pragma unroll
    for (int r = 0; r < RT; r++)
#pragma unroll
      for (int ct = 0; ct < 4; ct++){
        int o0 = (wave + 8*r)*16 + kg*4;
        int n  = ct*16 + lrow;
        u16x4 pk;
#pragma unroll
        for (int i = 0; i < 4; i++) pk[i] = f2b(lrelu((acc[r][ct][i] - mean)*sc));
        *(u16x4*)(Xout + (size_t)b*outStride + (size_t)n*O + o0) = pk;  // node-major
      }
  }
}

// ---------------------------------------------------------------------------
extern "C" void kernel_launch(void* const* d_in, const int* in_sizes, int n_in,
                              void* d_out, int out_size, void* d_ws, size_t ws_size,
                              hipStream_t stream)
{
  // ALL float inputs are float32 (proven by R3's dtype-flag experiment).
  const float* trees = (const float*)d_in[0];
  const int*   gidx  = (const int*)d_in[1];
  const float* w1 = (const float*)d_in[2];
  const float* g1 = (const float*)d_in[4];  const float* be1 = (const float*)d_in[5];
  const float* w2 = (const float*)d_in[6];
  const float* g2 = (const float*)d_in[8];  const float* be2 = (const float*)d_in[9];
  const float* w3 = (const float*)d_in[10];
  const float* g3 = (const float*)d_in[12]; const float* be3 = (const float*)d_in[13];
  const float* w4 = (const float*)d_in[14];
  const float* g4 = (const float*)d_in[16]; const float* be4 = (const float*)d_in[17];
  const float* cw1 = (const float*)d_in[18]; const float* cb1 = (const float*)d_in[19];
  const float* cw2 = (const float*)d_in[20]; const float* cb2 = (const float*)d_in[21];
  const float* cw3 = (const float*)d_in[22]; const float* cb3 = (const float*)d_in[23];
  // linear biases b1..b4 cancel under training-mode BN — unused.

  // ws (~33.3 MiB): repacked conv weights + BN scratch + Xc2.
  // Wr3 MUST be in ws (read by the final conv while d_out is being rewritten).
  // Xc2 MUST be in ws (conv2's slice-writes to d_out would race other blocks'
  // Xc2 reads if Xc2 lived in d_out).
  char* ws = (char*)d_ws;
  size_t off = 0;
  auto alloc = [&](size_t bytes)->char*{ char* p = ws + off; off += (bytes + 255) & ~(size_t)255; return p; };
  u16*   Wr1  = (u16*)  alloc(128*192*2);
  u16*   Wr2  = (u16*)  alloc(256*384*2);
  u16*   Wr3  = (u16*)  alloc(512*768*2);
  float* part = (float*)alloc(16*4096*4);
  float* ss1  = (float*)alloc(2*64*4);
  float* ss2  = (float*)alloc(2*256*4);
  float* ss3  = (float*)alloc(2*1024*4);
  float* ss4  = (float*)alloc(2*4096*4);
  u16*   Xc2  = (u16*)  alloc((size_t)2048*64*128*2);   // 32 MiB

  // d_out is (2048,512,64) FLOAT32 = 256 MiB. Host MLP-phase scratch inside it;
  // everything here is dead before conv2/conv3 touch d_out.
  float* outF = (float*)d_out;
  u16*   ob   = (u16*)d_out;                 // u16-unit view for offsets
  float* Y    = (float*)ob;                  // u16 [0, 16,777,216)  : f32 pre-BN (2048x4096)
  u16*   H1   = ob + 16777216;               // [16,777,216, 16,908,288)
  u16*   H2   = ob + 16908288;               // [.., 17,432,576)
  u16*   H3   = ob + 17432576;               // [.., 19,529,728)
  u16*   Tb   = ob + 19529728;               // [.., 19,660,800)
  u16*   Wb1  = ob + 19660800;               // [.., 19,664,896)
  u16*   Wb2  = ob + 19664896;               // [.., 19,681,280)
  u16*   Wb3  = ob + 19681280;               // [.., 19,943,424)
  u16*   Wb4  = ob + 19943424;               // [.., 24,137,728)
  u16*   Xt1  = ob + 25165824;               // [.., 33,554,432)
  // Xc3: per-sample, INSIDE sample b's own 65,536-u16 slice of d_out
  // (first 16,384 u16 of each slice). conv3 stages it fully to LDS before
  // overwriting the slice — race-free, no ws needed for the 64 MiB tensor.
  u16*   Xc3  = ob;                          // base 0, sample stride 65,536 u16

  // convert f32 inputs -> bf16 for MFMA
  cvt_bf16<<<(131072/4+255)/256, 256, 0, stream>>>(trees, Tb, 131072/4);
  cvt_bf16<<<(4096/4+255)/256,   256, 0, stream>>>(w1, Wb1, 4096/4);
  cvt_bf16<<<(16384/4+255)/256,  256, 0, stream>>>(w2, Wb2, 16384/4);
  cvt_bf16<<<(262144/4+255)/256, 256, 0, stream>>>(w3, Wb3, 262144/4);
  cvt_bf16<<<(4194304/4+255)/256,256, 0, stream>>>(w4, Wb4, 4194304/4);

  repack_w<<<(128*192+255)/256, 256, 0, stream>>>(cw1, Wr1, 128, 64, 6);
  repack_w<<<(256*384+255)/256, 256, 0, stream>>>(cw2, Wr2, 256, 128, 7);
  repack_w<<<(512*768+255)/256, 256, 0, stream>>>(cw3, Wr3, 512, 256, 8);

  // MLP layer 1: (2048,64)x(64,64)^T
  gemm_nt<64,64,4,1,1,4><<<dim3(32,1), 256, 0, stream>>>(Tb, Wb1, Y, 2048, 64, 64);
  bn_partial<<<dim3(1,8), 256, 0, stream>>>(Y, part, 64, 256);
  bn_finalize<<<1, 256, 0, stream>>>(part, g1, be1, ss1, 64, 2048, 8);
  bn_apply<<<(2048*64/4+255)/256, 256, 0, stream>>>(Y, ss1, H1, 2048*64/4, 64);
  // layer 2
  gemm_nt<64,64,4,1,1,4><<<dim3(32,4), 256, 0, stream>>>(H1, Wb2, Y, 2048, 256, 64);
  bn_partial<<<dim3(4,8), 256, 0, stream>>>(Y, part, 256, 256);
  bn_finalize<<<1, 256, 0, stream>>>(part, g2, be2, ss2, 256, 2048, 8);
  bn_apply<<<(2048*256/4+255)/256, 256, 0, stream>>>(Y, ss2, H2, 2048*256/4, 256);
  // layer 3
  gemm_nt<64,64,4,1,1,4><<<dim3(32,16), 256, 0, stream>>>(H2, Wb3, Y, 2048, 1024, 256);
  bn_partial<<<dim3(16,8), 256, 0, stream>>>(Y, part, 1024, 256);
  bn_finalize<<<4, 256, 0, stream>>>(part, g3, be3, ss3, 1024, 2048, 8);
  bn_apply<<<(2048*1024/4+255)/256, 256, 0, stream>>>(Y, ss3, H3, 2048*1024/4, 1024);
  // layer 4 (128x128 tiles)
  gemm_nt<128,128,2,2,4,4><<<dim3(16,32), 256, 0, stream>>>(H3, Wb4, Y, 2048, 4096, 1024);
  bn_partial<<<dim3(64,8), 256, 0, stream>>>(Y, part, 4096, 256);
  bn_finalize<<<16, 256, 0, stream>>>(part, g4, be4, ss4, 4096, 2048, 8);
  bn_apply4_t<<<2048, 256, 0, stream>>>(Y, ss4, Xt1);

  // tree-conv stack
  // conv1: Xt1 (d_out) -> Xc2 (ws)
  conv_norm< 64,128,false><<<2048, 512, 0, stream>>>(Xt1, 4096, Wr1, cb1, gidx, Xc2, 8192, nullptr);
  // conv2: Xc2 (ws) -> Xc3 slices (d_out, sample-strided 65,536 u16)
  conv_norm<128,256,false><<<2048, 512, 0, stream>>>(Xc2, 8192, Wr2, cb2, gidx, Xc3, 65536, nullptr);
  // conv3: Xc3 slices (d_out, staged to LDS first) -> final f32 output (d_out)
  conv_norm<256,512,true ><<<2048, 512, 0, stream>>>(Xc3, 65536, Wr3, cb3, gidx, nullptr, 0, outF);
}

// Round 3
// 739.693 us; speedup vs baseline: 1.1069x; 1.1069x over previous
//
#include <hip/hip_runtime.h>

typedef unsigned short u16;
typedef unsigned int   u32;
typedef __attribute__((ext_vector_type(8))) short short8;
typedef __attribute__((ext_vector_type(4))) float f32x4;
typedef __attribute__((ext_vector_type(4))) u16  u16x4;

#define DI __device__ __forceinline__

DI float b2f(u16 v){ return __builtin_bit_cast(float, (u32)v << 16); }
DI u16 f2b(float f){ u32 u = __builtin_bit_cast(u32, f); return (u16)((u + 0x7fffu + ((u >> 16) & 1u)) >> 16); }
DI float lrelu(float v){ return v > 0.f ? v : 0.01f * v; }

// ---------------- f32 -> bf16 conversion (inputs are float32 — proven R3) --
__global__ __launch_bounds__(256)
void cvt_bf16(const float* __restrict__ in, u16* __restrict__ out, int n4)
{
  int i = blockIdx.x*256 + threadIdx.x;
  if (i >= n4) return;
  float4 v = ((const float4*)in)[i];
  u16x4 o; o[0]=f2b(v.x); o[1]=f2b(v.y); o[2]=f2b(v.z); o[3]=f2b(v.w);
  *(u16x4*)(out + (size_t)i*4) = o;
}

// ---------------- GEMM (NT): Y[M,N] = A[M,K] * W[N,K]^T, f32 out -----------
template<int BM, int BN, int WROWS, int WCOLS, int RT, int CT>
__global__ __launch_bounds__(WROWS*WCOLS*64)
void gemm_nt(const u16* __restrict__ A, const u16* __restrict__ W,
             float* __restrict__ Y, int M, int N, int K)
{
  constexpr int NT  = WROWS*WCOLS*64;
  constexpr int ALD = (BM*4)/NT;
  constexpr int BLD = (BN*4)/NT;
  __shared__ __align__(16) u16 As[BM*32];
  __shared__ __align__(16) u16 Bs[BN*32];
  const int tid  = threadIdx.x;
  const int wave = tid >> 6, lane = tid & 63;
  const int wr = wave / WCOLS, wc = wave % WCOLS;
  const int lrow = lane & 15, kg = lane >> 4;
  const int m0 = blockIdx.x * BM, n0 = blockIdx.y * BN;
  f32x4 acc[RT][CT] = {};
  for (int k0 = 0; k0 < K; k0 += 32) {
    uint4 av[ALD], bv[BLD];
#pragma unroll
    for (int i = 0; i < ALD; i++){ int x = tid + i*NT; av[i] = *(const uint4*)(A + (size_t)(m0 + (x>>2))*K + k0 + (x&3)*8); }
#pragma unroll
    for (int i = 0; i < BLD; i++){ int x = tid + i*NT; bv[i] = *(const uint4*)(W + (size_t)(n0 + (x>>2))*K + k0 + (x&3)*8); }
    __syncthreads();
#pragma unroll
    for (int i = 0; i < ALD; i++){ *(uint4*)(As + (tid + i*NT)*8) = av[i]; }
#pragma unroll
    for (int i = 0; i < BLD; i++){ *(uint4*)(Bs + (tid + i*NT)*8) = bv[i]; }
    __syncthreads();
    short8 af[RT], bfr[CT];
#pragma unroll
    for (int r = 0; r < RT; r++) af[r]  = *(const short8*)(As + ((wr*RT + r)*16 + lrow)*32 + kg*8);
#pragma unroll
    for (int c = 0; c < CT; c++) bfr[c] = *(const short8*)(Bs + ((wc*CT + c)*16 + lrow)*32 + kg*8);
#pragma unroll
    for (int r = 0; r < RT; r++)
#pragma unroll
      for (int c = 0; c < CT; c++)
        acc[r][c] = __builtin_amdgcn_mfma_f32_16x16x32_bf16(af[r], bfr[c], acc[r][c], 0, 0, 0);
  }
  // C/D: col=lane&15, row=(lane>>4)*4+i  [m89/m91]
#pragma unroll
  for (int r = 0; r < RT; r++)
#pragma unroll
    for (int c = 0; c < CT; c++)
#pragma unroll
      for (int i = 0; i < 4; i++){
        int m = m0 + (wr*RT + r)*16 + kg*4 + i;
        int n = n0 + (wc*CT + c)*16 + lrow;
        Y[(size_t)m*N + n] = acc[r][c][i];
      }
}

// ---------------- BatchNorm (training-mode, batch stats), Y f32 ------------
__global__ __launch_bounds__(256)
void bn_partial(const float* __restrict__ Y, float* __restrict__ part, int N, int rowsPer)
{
  const int tx = threadIdx.x & 63, ty = threadIdx.x >> 6;
  const int n  = blockIdx.x*64 + tx;
  const int m0 = blockIdx.y * rowsPer;
  float s = 0.f, s2 = 0.f;
  for (int m = m0 + ty; m < m0 + rowsPer; m += 4){ float v = Y[(size_t)m*N + n]; s += v; s2 += v*v; }
  __shared__ float ls[4][64], ls2[4][64];
  ls[ty][tx] = s; ls2[ty][tx] = s2;
  __syncthreads();
  if (ty == 0){
    s  = ls[0][tx]+ls[1][tx]+ls[2][tx]+ls[3][tx];
    s2 = ls2[0][tx]+ls2[1][tx]+ls2[2][tx]+ls2[3][tx];
    part[(size_t)(blockIdx.y*2+0)*N + n] = s;
    part[(size_t)(blockIdx.y*2+1)*N + n] = s2;
  }
}

__global__ __launch_bounds__(256)
void bn_finalize(const float* __restrict__ part, const float* __restrict__ g,
                 const float* __restrict__ be, float* __restrict__ ss, int N, int M, int split)
{
  int n = blockIdx.x*256 + threadIdx.x;
  if (n >= N) return;
  float s = 0.f, s2 = 0.f;
  for (int i = 0; i < split; i++){ s += part[(size_t)(i*2+0)*N + n]; s2 += part[(size_t)(i*2+1)*N + n]; }
  float inv  = 1.f / (float)M;
  float mean = s * inv;
  float var  = fmaxf(s2*inv - mean*mean, 0.f);
  float sc   = g[n] * rsqrtf(var + 1e-5f);
  ss[n]     = sc;
  ss[N + n] = be[n] - mean*sc;
}

__global__ __launch_bounds__(256)
void bn_apply(const float* __restrict__ Y, const float* __restrict__ ss,
              u16* __restrict__ H, int total4, int N)
{
  int i = blockIdx.x*256 + threadIdx.x;
  if (i >= total4) return;
  float4 v = ((const float4*)Y)[i];
  int nb = (i*4) & (N-1);
  u16x4 o;
  o[0] = f2b(lrelu(v.x*ss[nb+0] + ss[N+nb+0]));
  o[1] = f2b(lrelu(v.y*ss[nb+1] + ss[N+nb+1]));
  o[2] = f2b(lrelu(v.z*ss[nb+2] + ss[N+nb+2]));
  o[3] = f2b(lrelu(v.w*ss[nb+3] + ss[N+nb+3]));
  *(u16x4*)(H + (size_t)i*4) = o;
}

// BN apply layer-4 + per-sample transpose: Xt[b][n][c] = lrelu(bn(h4))[b][c*64+n]
__global__ __launch_bounds__(256)
void bn_apply4_t(const float* __restrict__ Y, const float* __restrict__ ss, u16* __restrict__ Xt)
{
  const int b = blockIdx.x, tid = threadIdx.x;
  __shared__ u16 t[64*65];
  for (int j = tid; j < 4096; j += 256){
    float v = Y[(size_t)b*4096 + j];
    v = lrelu(v*ss[j] + ss[4096 + j]);
    int c = j >> 6, n = j & 63;
    t[c*65 + n] = f2b(v);
  }
  __syncthreads();
  for (int e = tid; e < 4096; e += 256){
    int n = e >> 6, c = e & 63;
    Xt[(size_t)b*4096 + n*64 + c] = t[c*65 + n];
  }
}

// ---------------- conv weight repack: wr[o][k*C+c] = w[o][c*3+k], f32 in ---
__global__ __launch_bounds__(256)
void repack_w(const float* __restrict__ w, u16* __restrict__ wr, int O, int C, int lgC)
{
  int e = blockIdx.x*256 + threadIdx.x;
  int R = 3*C;
  if (e >= O*R) return;
  int o = e / R; int r = e - o*R;
  int k = r >> lgC; int c = r & (C-1);
  wr[e] = f2b(w[(size_t)o*R + c*3 + k]);
}

// ---------------- tree-conv + TreeLayerNorm + LeakyReLU --------------------
// S samples per block: weight fragments (global loads) are reused across S
// samples' MFMAs — weight traffic /S and S× MFMA work per load latency.
// Xin: per-sample base = Xin + b*inStride, node-major (64, C) bf16.
// non-LAST out: per-sample base = Xout + b*outStride, node-major (64, O) bf16.
// LAST: Outf + b*O*64, (O, 64) f32.
// Aliasing note: each block stages ALL its samples' inputs into LDS before
// writing any output, and touches only its own samples' slices.
template<int C, int O, bool LAST, int S>
__global__ __launch_bounds__(512)
void conv_norm(const u16* __restrict__ Xin, long inStride,
               const u16* __restrict__ Wr,
               const float* __restrict__ cb, const int* __restrict__ gidx,
               u16* __restrict__ Xout, long outStride, float* __restrict__ Outf)
{
  constexpr int R   = 3*C;
  constexpr int CSI = C + 8;
  constexpr int XS  = 65*CSI;          // per-sample LDS stride (u16)
  constexpr int RT  = O/128;
  constexpr int LGC = (C==64)?6:((C==128)?7:8);
  constexpr int CH8 = C/8;
  __shared__ __align__(16) u16 xs[S*XS];
  __shared__ int idxs[S*192];
  __shared__ float red[S*16];
  __shared__ float res[S*2];
  const int b0 = blockIdx.x * S, tid = threadIdx.x;
  const int wave = tid >> 6, lane = tid & 63;
  const int lrow = lane & 15, kg = lane >> 4;

#pragma unroll
  for (int s = 0; s < S; s++){
    const u16* xg = Xin + (size_t)(b0 + s)*inStride;
    u16* xd = xs + s*XS;
    for (int e = tid; e < 64*CH8; e += 512){
      int row = e / CH8, t = e % CH8;
      *(uint4*)(xd + row*CSI + t*8) = *(const uint4*)(xg + row*C + t*8);
    }
    if (tid < CH8){ uint4 z = {0,0,0,0}; *(uint4*)(xd + 64*CSI + tid*8) = z; }
    if (tid < 189) idxs[s*192 + tid] = gidx[(size_t)(b0 + s)*189 + tid] & 63;
  }
  __syncthreads();

  int jt[S][4][3];
#pragma unroll
  for (int s = 0; s < S; s++)
#pragma unroll
    for (int ct = 0; ct < 4; ct++){
      int n = ct*16 + lrow;
#pragma unroll
      for (int k = 0; k < 3; k++) jt[s][ct][k] = (n == 0) ? 64 : idxs[s*192 + 3*(n-1) + k];
    }

  f32x4 acc[RT][4][S] = {};
#pragma unroll
  for (int kb = 0; kb < R; kb += 32){
    constexpr int dummy = 0; (void)dummy;
    const int k  = kb >> LGC;            // compile-time after unroll
    const int c0 = (kb & (C-1)) + kg*8;
    short8 af[RT];
#pragma unroll
    for (int r = 0; r < RT; r++) af[r] = *(const short8*)(Wr + (size_t)((wave + 8*r)*16 + lrow)*R + kb + kg*8);
#pragma unroll
    for (int s = 0; s < S; s++){
      short8 bfr[4];
#pragma unroll
      for (int ct = 0; ct < 4; ct++) bfr[ct] = *(const short8*)(xs + s*XS + jt[s][ct][k]*CSI + c0);
#pragma unroll
      for (int r = 0; r < RT; r++)
#pragma unroll
        for (int ct = 0; ct < 4; ct++)
          acc[r][ct][s] = __builtin_amdgcn_mfma_f32_16x16x32_bf16(af[r], bfr[ct], acc[r][ct][s], 0, 0, 0);
    }
  }

  // bias (skip null column 0) + per-sample stats over (O x 64)
  float sv[S], sv2[S];
#pragma unroll
  for (int s = 0; s < S; s++){ sv[s] = 0.f; sv2[s] = 0.f; }
#pragma unroll
  for (int r = 0; r < RT; r++)
#pragma unroll
    for (int i = 0; i < 4; i++){
      int o = (wave + 8*r)*16 + kg*4 + i;
      float bias = cb[o];
#pragma unroll
      for (int ct = 0; ct < 4; ct++){
        int n = ct*16 + lrow;
#pragma unroll
        for (int s = 0; s < S; s++){
          float v = acc[r][ct][s][i];
          if (n != 0) v += bias;
          acc[r][ct][s][i] = v;
          sv[s] += v; sv2[s] += v*v;
        }
      }
    }
#pragma unroll
  for (int s = 0; s < S; s++){
#pragma unroll
    for (int off = 32; off > 0; off >>= 1){ sv[s] += __shfl_down(sv[s], off); sv2[s] += __shfl_down(sv2[s], off); }
    if (lane == 0){ red[s*16 + wave] = sv[s]; red[s*16 + 8 + wave] = sv2[s]; }
  }
  __syncthreads();
  if (tid < S){
    float Sm = 0.f, S2 = 0.f;
    for (int w = 0; w < 8; w++){ Sm += red[tid*16 + w]; S2 += red[tid*16 + 8 + w]; }
    const float NV = (float)(O*64);
    float mean = Sm / NV;
    float var  = fmaxf(S2/NV - mean*mean, 0.f) * (NV/(NV-1.f));  // torch.std ddof=1
    float sc   = 1.f / (sqrtf(var) + 1e-5f);
    res[tid*2 + 0] = mean; res[tid*2 + 1] = sc;
  }
  __syncthreads();

#pragma unroll
  for (int s = 0; s < S; s++){
    const float mean = res[s*2 + 0], sc = res[s*2 + 1];
    if constexpr (LAST) {
#pragma unroll
      for (int r = 0; r < RT; r++)
#pragma unroll
        for (int ct = 0; ct < 4; ct++)
#pragma unroll
          for (int i = 0; i < 4; i++){
            int o = (wave + 8*r)*16 + kg*4 + i;
            int n = ct*16 + lrow;
            Outf[(size_t)(b0 + s)*(O*64) + o*64 + n] = lrelu((acc[r][ct][s][i] - mean)*sc);
          }
    } else {
#pragma unroll
      for (int r = 0; r < RT; r++)
#pragma unroll
        for (int ct = 0; ct < 4; ct++){
          int o0 = (wave + 8*r)*16 + kg*4;
          int n  = ct*16 + lrow;
          u16x4 pk;
#pragma unroll
          for (int i = 0; i < 4; i++) pk[i] = f2b(lrelu((acc[r][ct][s][i] - mean)*sc));
          *(u16x4*)(Xout + (size_t)(b0 + s)*outStride + (size_t)n*O + o0) = pk;
        }
    }
  }
}

// ---------------------------------------------------------------------------
extern "C" void kernel_launch(void* const* d_in, const int* in_sizes, int n_in,
                              void* d_out, int out_size, void* d_ws, size_t ws_size,
                              hipStream_t stream)
{
  // ALL float inputs are float32 (proven by R3's dtype-flag experiment).
  const float* trees = (const float*)d_in[0];
  const int*   gidx  = (const int*)d_in[1];
  const float* w1 = (const float*)d_in[2];
  const float* g1 = (const float*)d_in[4];  const float* be1 = (const float*)d_in[5];
  const float* w2 = (const float*)d_in[6];
  const float* g2 = (const float*)d_in[8];  const float* be2 = (const float*)d_in[9];
  const float* w3 = (const float*)d_in[10];
  const float* g3 = (const float*)d_in[12]; const float* be3 = (const float*)d_in[13];
  const float* w4 = (const float*)d_in[14];
  const float* g4 = (const float*)d_in[16]; const float* be4 = (const float*)d_in[17];
  const float* cw1 = (const float*)d_in[18]; const float* cb1 = (const float*)d_in[19];
  const float* cw2 = (const float*)d_in[20]; const float* cb2 = (const float*)d_in[21];
  const float* cw3 = (const float*)d_in[22]; const float* cb3 = (const float*)d_in[23];
  // linear biases b1..b4 cancel under training-mode BN — unused.

  // ws (~33.3 MiB): repacked conv weights + BN scratch + Xc2.
  // Wr3 MUST be in ws (read by the final conv while d_out is being rewritten).
  // Xc2 MUST be in ws (conv2's slice-writes to d_out would race other blocks'
  // Xc2 reads if Xc2 lived in d_out).
  char* ws = (char*)d_ws;
  size_t off = 0;
  auto alloc = [&](size_t bytes)->char*{ char* p = ws + off; off += (bytes + 255) & ~(size_t)255; return p; };
  u16*   Wr1  = (u16*)  alloc(128*192*2);
  u16*   Wr2  = (u16*)  alloc(256*384*2);
  u16*   Wr3  = (u16*)  alloc(512*768*2);
  float* part = (float*)alloc(16*4096*4);
  float* ss1  = (float*)alloc(2*64*4);
  float* ss2  = (float*)alloc(2*256*4);
  float* ss3  = (float*)alloc(2*1024*4);
  float* ss4  = (float*)alloc(2*4096*4);
  u16*   Xc2  = (u16*)  alloc((size_t)2048*64*128*2);   // 32 MiB

  // d_out is (2048,512,64) FLOAT32 = 256 MiB. Host MLP-phase scratch inside it;
  // everything here is dead before conv2/conv3 touch d_out.
  float* outF = (float*)d_out;
  u16*   ob   = (u16*)d_out;                 // u16-unit view for offsets
  float* Y    = (float*)ob;                  // u16 [0, 16,777,216)  : f32 pre-BN (2048x4096)
  u16*   H1   = ob + 16777216;               // [16,777,216, 16,908,288)
  u16*   H2   = ob + 16908288;               // [.., 17,432,576)
  u16*   H3   = ob + 17432576;               // [.., 19,529,728)
  u16*   Tb   = ob + 19529728;               // [.., 19,660,800)
  u16*   Wb1  = ob + 19660800;               // [.., 19,664,896)
  u16*   Wb2  = ob + 19664896;               // [.., 19,681,280)
  u16*   Wb3  = ob + 19681280;               // [.., 19,943,424)
  u16*   Wb4  = ob + 19943424;               // [.., 24,137,728)
  u16*   Xt1  = ob + 25165824;               // [.., 33,554,432)
  // Xc3: per-sample, INSIDE sample b's own 65,536-u16 slice of d_out
  // (first 16,384 u16 of each slice). conv3 stages it fully to LDS before
  // overwriting the slice — race-free, no ws needed for the 64 MiB tensor.
  u16*   Xc3  = ob;                          // base 0, sample stride 65,536 u16

  // convert f32 inputs -> bf16 for MFMA
  cvt_bf16<<<(131072/4+255)/256, 256, 0, stream>>>(trees, Tb, 131072/4);
  cvt_bf16<<<(4096/4+255)/256,   256, 0, stream>>>(w1, Wb1, 4096/4);
  cvt_bf16<<<(16384/4+255)/256,  256, 0, stream>>>(w2, Wb2, 16384/4);
  cvt_bf16<<<(262144/4+255)/256, 256, 0, stream>>>(w3, Wb3, 262144/4);
  cvt_bf16<<<(4194304/4+255)/256,256, 0, stream>>>(w4, Wb4, 4194304/4);

  repack_w<<<(128*192+255)/256, 256, 0, stream>>>(cw1, Wr1, 128, 64, 6);
  repack_w<<<(256*384+255)/256, 256, 0, stream>>>(cw2, Wr2, 256, 128, 7);
  repack_w<<<(512*768+255)/256, 256, 0, stream>>>(cw3, Wr3, 512, 256, 8);

  // MLP layer 1: (2048,64)x(64,64)^T
  gemm_nt<64,64,4,1,1,4><<<dim3(32,1), 256, 0, stream>>>(Tb, Wb1, Y, 2048, 64, 64);
  bn_partial<<<dim3(1,8), 256, 0, stream>>>(Y, part, 64, 256);
  bn_finalize<<<1, 256, 0, stream>>>(part, g1, be1, ss1, 64, 2048, 8);
  bn_apply<<<(2048*64/4+255)/256, 256, 0, stream>>>(Y, ss1, H1, 2048*64/4, 64);
  // layer 2
  gemm_nt<64,64,4,1,1,4><<<dim3(32,4), 256, 0, stream>>>(H1, Wb2, Y, 2048, 256, 64);
  bn_partial<<<dim3(4,8), 256, 0, stream>>>(Y, part, 256, 256);
  bn_finalize<<<1, 256, 0, stream>>>(part, g2, be2, ss2, 256, 2048, 8);
  bn_apply<<<(2048*256/4+255)/256, 256, 0, stream>>>(Y, ss2, H2, 2048*256/4, 256);
  // layer 3
  gemm_nt<64,64,4,1,1,4><<<dim3(32,16), 256, 0, stream>>>(H2, Wb3, Y, 2048, 1024, 256);
  bn_partial<<<dim3(16,8), 256, 0, stream>>>(Y, part, 1024, 256);
  bn_finalize<<<4, 256, 0, stream>>>(part, g3, be3, ss3, 1024, 2048, 8);
  bn_apply<<<(2048*1024/4+255)/256, 256, 0, stream>>>(Y, ss3, H3, 2048*1024/4, 1024);
  // layer 4 (128x128 tiles)
  gemm_nt<128,128,2,2,4,4><<<dim3(16,32), 256, 0, stream>>>(H3, Wb4, Y, 2048, 4096, 1024);
  bn_partial<<<dim3(64,8), 256, 0, stream>>>(Y, part, 4096, 256);
  bn_finalize<<<16, 256, 0, stream>>>(part, g4, be4, ss4, 4096, 2048, 8);
  bn_apply4_t<<<2048, 256, 0, stream>>>(Y, ss4, Xt1);

  // tree-conv stack (S samples per block: weight reuse across samples)
  // conv1: Xt1 (d_out) -> Xc2 (ws)
  conv_norm< 64,128,false,4><<< 512, 512, 0, stream>>>(Xt1, 4096, Wr1, cb1, gidx, Xc2, 8192, nullptr);
  // conv2: Xc2 (ws) -> Xc3 slices (d_out, sample-strided 65,536 u16)
  conv_norm<128,256,false,2><<<1024, 512, 0, stream>>>(Xc2, 8192, Wr2, cb2, gidx, Xc3, 65536, nullptr);
  // conv3: Xc3 slices (d_out, staged to LDS first) -> final f32 output (d_out)
  conv_norm<256,512,true ,2><<<1024, 512, 0, stream>>>(Xc3, 65536, Wr3, cb3, gidx, nullptr, 0, outF);
}

// Round 4
// 641.186 us; speedup vs baseline: 1.2770x; 1.1536x over previous
//
#include <hip/hip_runtime.h>

typedef unsigned short u16;
typedef unsigned int   u32;
typedef __attribute__((ext_vector_type(8))) short short8;
typedef __attribute__((ext_vector_type(4))) float f32x4;
typedef __attribute__((ext_vector_type(4))) u16  u16x4;

#define DI __device__ __forceinline__

DI float b2f(u16 v){ return __builtin_bit_cast(float, (u32)v << 16); }
DI u16 f2b(float f){ u32 u = __builtin_bit_cast(u32, f); return (u16)((u + 0x7fffu + ((u >> 16) & 1u)) >> 16); }
DI float lrelu(float v){ return v > 0.f ? v : 0.01f * v; }

// ---------------- zero BN-stat accumulators (re-run every replay) ----------
__global__ __launch_bounds__(256)
void zero_buf(float* __restrict__ p, int n)
{
  int i = blockIdx.x*256 + threadIdx.x;
  if (i < n) p[i] = 0.f;
}

// ---------------- merged f32 -> bf16 conversion (5 segments) ---------------
__global__ __launch_bounds__(256)
void cvt5(const float* __restrict__ a0, u16* __restrict__ o0, int n0,
          const float* __restrict__ a1, u16* __restrict__ o1, int n1,
          const float* __restrict__ a2, u16* __restrict__ o2, int n2,
          const float* __restrict__ a3, u16* __restrict__ o3, int n3,
          const float* __restrict__ a4, u16* __restrict__ o4, int n4)
{
  int i = blockIdx.x*256 + threadIdx.x;
  const float* in; u16* out; int loc = i;
  if      (loc < n0){ in = a0; out = o0; }
  else if ((loc -= n0) < n1){ in = a1; out = o1; }
  else if ((loc -= n1) < n2){ in = a2; out = o2; }
  else if ((loc -= n2) < n3){ in = a3; out = o3; }
  else if ((loc -= n3) < n4){ in = a4; out = o4; }
  else return;
  float4 v = ((const float4*)in)[loc];
  u16x4 o; o[0]=f2b(v.x); o[1]=f2b(v.y); o[2]=f2b(v.z); o[3]=f2b(v.w);
  *(u16x4*)(out + (size_t)loc*4) = o;
}

// ---------------- merged conv weight repack: wr[o][k*C+c] = w[o][c*3+k] ----
__global__ __launch_bounds__(256)
void repack3(const float* __restrict__ cw1, u16* __restrict__ Wr1,
             const float* __restrict__ cw2, u16* __restrict__ Wr2,
             const float* __restrict__ cw3, u16* __restrict__ Wr3)
{
  int e = blockIdx.x*256 + threadIdx.x;
  const float* w; u16* wr; int C, lgC; int loc = e;
  if      (loc < 24576){ w = cw1; wr = Wr1; C = 64;  lgC = 6; }
  else if ((loc -= 24576) < 98304){ w = cw2; wr = Wr2; C = 128; lgC = 7; }
  else if ((loc -= 98304) < 393216){ w = cw3; wr = Wr3; C = 256; lgC = 8; }
  else return;
  int R = 3*C;
  int o = loc / R; int r = loc - o*R;
  int k = r >> lgC; int c = r & (C-1);
  wr[loc] = f2b(w[(size_t)o*R + c*3 + k]);
}

// ---------------- GEMM (NT): Y[M,N] = A[M,K] * W[N,K]^T, f32 out -----------
// APPLYA: A comes as f32 (prev layer's pre-BN Y) + ssA [scale(K), shift(K)];
//         staging applies v*sc+sh, lrelu, bf16-cast (bit-identical to the old
//         separate bn_apply pass).
// STATS:  per-block column sums/sumsq of the f32 output are reduced in LDS
//         and atomicAdd'ed into part [sum(N), sumsq(N)] (zeroed per replay).
template<int BM, int BN, int WROWS, int WCOLS, int RT, int CT, bool APPLYA, bool STATS>
__global__ __launch_bounds__(WROWS*WCOLS*64)
void gemm_nt(const u16* __restrict__ A, const float* __restrict__ Af,
             const u16* __restrict__ W, float* __restrict__ Y,
             const float* __restrict__ ssA, float* __restrict__ part,
             int M, int N, int K)
{
  constexpr int NT  = WROWS*WCOLS*64;
  constexpr int ALD = (BM*4)/NT;
  constexpr int BLD = (BN*4)/NT;
  __shared__ __align__(16) u16 As[BM*32];
  __shared__ __align__(16) u16 Bs[BN*32];
  const int tid  = threadIdx.x;
  const int wave = tid >> 6, lane = tid & 63;
  const int wr = wave / WCOLS, wc = wave % WCOLS;
  const int lrow = lane & 15, kg = lane >> 4;
  const int m0 = blockIdx.x * BM, n0 = blockIdx.y * BN;
  f32x4 acc[RT][CT] = {};
  for (int k0 = 0; k0 < K; k0 += 32) {
    uint4 av[ALD], bv[BLD];
    if constexpr (APPLYA){
#pragma unroll
      for (int i = 0; i < ALD; i++){
        int x = tid + i*NT; int row = m0 + (x>>2); int c0 = k0 + (x&3)*8;
        const float* ap = Af + (size_t)row*K + c0;
        float4 f0 = *(const float4*)ap;
        float4 f1 = *(const float4*)(ap + 4);
        u32 p0 = (u32)f2b(lrelu(f0.x*ssA[c0+0] + ssA[K+c0+0]))
               | ((u32)f2b(lrelu(f0.y*ssA[c0+1] + ssA[K+c0+1])) << 16);
        u32 p1 = (u32)f2b(lrelu(f0.z*ssA[c0+2] + ssA[K+c0+2]))
               | ((u32)f2b(lrelu(f0.w*ssA[c0+3] + ssA[K+c0+3])) << 16);
        u32 p2 = (u32)f2b(lrelu(f1.x*ssA[c0+4] + ssA[K+c0+4]))
               | ((u32)f2b(lrelu(f1.y*ssA[c0+5] + ssA[K+c0+5])) << 16);
        u32 p3 = (u32)f2b(lrelu(f1.z*ssA[c0+6] + ssA[K+c0+6]))
               | ((u32)f2b(lrelu(f1.w*ssA[c0+7] + ssA[K+c0+7])) << 16);
        av[i] = uint4{p0, p1, p2, p3};
      }
    } else {
#pragma unroll
      for (int i = 0; i < ALD; i++){ int x = tid + i*NT; av[i] = *(const uint4*)(A + (size_t)(m0 + (x>>2))*K + k0 + (x&3)*8); }
    }
#pragma unroll
    for (int i = 0; i < BLD; i++){ int x = tid + i*NT; bv[i] = *(const uint4*)(W + (size_t)(n0 + (x>>2))*K + k0 + (x&3)*8); }
    __syncthreads();
#pragma unroll
    for (int i = 0; i < ALD; i++){ *(uint4*)(As + (tid + i*NT)*8) = av[i]; }
#pragma unroll
    for (int i = 0; i < BLD; i++){ *(uint4*)(Bs + (tid + i*NT)*8) = bv[i]; }
    __syncthreads();
    short8 af[RT], bfr[CT];
#pragma unroll
    for (int r = 0; r < RT; r++) af[r]  = *(const short8*)(As + ((wr*RT + r)*16 + lrow)*32 + kg*8);
#pragma unroll
    for (int c = 0; c < CT; c++) bfr[c] = *(const short8*)(Bs + ((wc*CT + c)*16 + lrow)*32 + kg*8);
#pragma unroll
    for (int r = 0; r < RT; r++)
#pragma unroll
      for (int c = 0; c < CT; c++)
        acc[r][c] = __builtin_amdgcn_mfma_f32_16x16x32_bf16(af[r], bfr[c], acc[r][c], 0, 0, 0);
  }
  // C/D: col=lane&15, row=(lane>>4)*4+i  [m89/m91]
#pragma unroll
  for (int r = 0; r < RT; r++)
#pragma unroll
    for (int c = 0; c < CT; c++)
#pragma unroll
      for (int i = 0; i < 4; i++){
        int m = m0 + (wr*RT + r)*16 + kg*4 + i;
        int n = n0 + (wc*CT + c)*16 + lrow;
        Y[(size_t)m*N + n] = acc[r][c][i];
      }

  if constexpr (STATS){
    __shared__ float cs[BN], cs2[BN];
    for (int t = tid; t < BN; t += NT){ cs[t] = 0.f; cs2[t] = 0.f; }
    __syncthreads();
#pragma unroll
    for (int c = 0; c < CT; c++){
      float ls = 0.f, ls2 = 0.f;
#pragma unroll
      for (int r = 0; r < RT; r++)
#pragma unroll
        for (int i = 0; i < 4; i++){ float v = acc[r][c][i]; ls += v; ls2 += v*v; }
      ls  += __shfl_down(ls, 32);  ls  += __shfl_down(ls, 16);
      ls2 += __shfl_down(ls2, 32); ls2 += __shfl_down(ls2, 16);
      if (lane < 16){
        atomicAdd(&cs [(wc*CT + c)*16 + lrow], ls);
        atomicAdd(&cs2[(wc*CT + c)*16 + lrow], ls2);
      }
    }
    __syncthreads();
    for (int t = tid; t < BN; t += NT){
      atomicAdd(part + n0 + t,     cs[t]);
      atomicAdd(part + N + n0 + t, cs2[t]);
    }
  }
}

// ---------------- BN finalize: part row -> scale/shift ---------------------
__global__ __launch_bounds__(256)
void bn_finalize(const float* __restrict__ part, const float* __restrict__ g,
                 const float* __restrict__ be, float* __restrict__ ss, int N, int M)
{
  int n = blockIdx.x*256 + threadIdx.x;
  if (n >= N) return;
  float s = part[n], s2 = part[N + n];
  float inv  = 1.f / (float)M;
  float mean = s * inv;
  float var  = fmaxf(s2*inv - mean*mean, 0.f);
  float sc   = g[n] * rsqrtf(var + 1e-5f);
  ss[n]     = sc;
  ss[N + n] = be[n] - mean*sc;
}

// BN apply layer-4 + per-sample transpose: Xt[b][n][c] = lrelu(bn(h4))[b][c*64+n]
__global__ __launch_bounds__(256)
void bn_apply4_t(const float* __restrict__ Y, const float* __restrict__ ss, u16* __restrict__ Xt)
{
  const int b = blockIdx.x, tid = threadIdx.x;
  __shared__ u16 t[64*65];
  for (int j = tid; j < 4096; j += 256){
    float v = Y[(size_t)b*4096 + j];
    v = lrelu(v*ss[j] + ss[4096 + j]);
    int c = j >> 6, n = j & 63;
    t[c*65 + n] = f2b(v);
  }
  __syncthreads();
  for (int e = tid; e < 4096; e += 256){
    int n = e >> 6, c = e & 63;
    Xt[(size_t)b*4096 + n*64 + c] = t[c*65 + n];
  }
}

// ---------------- tree-conv + TreeLayerNorm + LeakyReLU --------------------
// S samples per block: weight fragments (global loads) are reused across S
// samples' MFMAs — weight traffic /S and S× MFMA work per load latency.
// Xin: per-sample base = Xin + b*inStride, node-major (64, C) bf16.
// non-LAST out: per-sample base = Xout + b*outStride, node-major (64, O) bf16.
// LAST: Outf + b*O*64, (O, 64) f32.
// Aliasing note: each block stages ALL its samples' inputs into LDS before
// writing any output, and touches only its own samples' slices.
template<int C, int O, bool LAST, int S>
__global__ __launch_bounds__(512)
void conv_norm(const u16* __restrict__ Xin, long inStride,
               const u16* __restrict__ Wr,
               const float* __restrict__ cb, const int* __restrict__ gidx,
               u16* __restrict__ Xout, long outStride, float* __restrict__ Outf)
{
  constexpr int R   = 3*C;
  constexpr int CSI = C + 8;
  constexpr int XS  = 65*CSI;          // per-sample LDS stride (u16)
  constexpr int RT  = O/128;
  constexpr int LGC = (C==64)?6:((C==128)?7:8);
  constexpr int CH8 = C/8;
  __shared__ __align__(16) u16 xs[S*XS];
  __shared__ int idxs[S*192];
  __shared__ float red[S*16];
  __shared__ float res[S*2];
  const int b0 = blockIdx.x * S, tid = threadIdx.x;
  const int wave = tid >> 6, lane = tid & 63;
  const int lrow = lane & 15, kg = lane >> 4;

#pragma unroll
  for (int s = 0; s < S; s++){
    const u16* xg = Xin + (size_t)(b0 + s)*inStride;
    u16* xd = xs + s*XS;
    for (int e = tid; e < 64*CH8; e += 512){
      int row = e / CH8, t = e % CH8;
      *(uint4*)(xd + row*CSI + t*8) = *(const uint4*)(xg + row*C + t*8);
    }
    if (tid < CH8){ uint4 z = {0,0,0,0}; *(uint4*)(xd + 64*CSI + tid*8) = z; }
    if (tid < 189) idxs[s*192 + tid] = gidx[(size_t)(b0 + s)*189 + tid] & 63;
  }
  __syncthreads();

  int jt[S][4][3];
#pragma unroll
  for (int s = 0; s < S; s++)
#pragma unroll
    for (int ct = 0; ct < 4; ct++){
      int n = ct*16 + lrow;
#pragma unroll
      for (int k = 0; k < 3; k++) jt[s][ct][k] = (n == 0) ? 64 : idxs[s*192 + 3*(n-1) + k];
    }

  f32x4 acc[RT][4][S] = {};
#pragma unroll
  for (int kb = 0; kb < R; kb += 32){
    const int k  = kb >> LGC;            // compile-time after unroll
    const int c0 = (kb & (C-1)) + kg*8;
    short8 af[RT];
#pragma unroll
    for (int r = 0; r < RT; r++) af[r] = *(const short8*)(Wr + (size_t)((wave + 8*r)*16 + lrow)*R + kb + kg*8);
#pragma unroll
    for (int s = 0; s < S; s++){
      short8 bfr[4];
#pragma unroll
      for (int ct = 0; ct < 4; ct++) bfr[ct] = *(const short8*)(xs + s*XS + jt[s][ct][k]*CSI + c0);
#pragma unroll
      for (int r = 0; r < RT; r++)
#pragma unroll
        for (int ct = 0; ct < 4; ct++)
          acc[r][ct][s] = __builtin_amdgcn_mfma_f32_16x16x32_bf16(af[r], bfr[ct], acc[r][ct][s], 0, 0, 0);
    }
  }

  // bias (skip null column 0) + per-sample stats over (O x 64)
  float sv[S], sv2[S];
#pragma unroll
  for (int s = 0; s < S; s++){ sv[s] = 0.f; sv2[s] = 0.f; }
#pragma unroll
  for (int r = 0; r < RT; r++)
#pragma unroll
    for (int i = 0; i < 4; i++){
      int o = (wave + 8*r)*16 + kg*4 + i;
      float bias = cb[o];
#pragma unroll
      for (int ct = 0; ct < 4; ct++){
        int n = ct*16 + lrow;
#pragma unroll
        for (int s = 0; s < S; s++){
          float v = acc[r][ct][s][i];
          if (n != 0) v += bias;
          acc[r][ct][s][i] = v;
          sv[s] += v; sv2[s] += v*v;
        }
      }
    }
#pragma unroll
  for (int s = 0; s < S; s++){
#pragma unroll
    for (int off = 32; off > 0; off >>= 1){ sv[s] += __shfl_down(sv[s], off); sv2[s] += __shfl_down(sv2[s], off); }
    if (lane == 0){ red[s*16 + wave] = sv[s]; red[s*16 + 8 + wave] = sv2[s]; }
  }
  __syncthreads();
  if (tid < S){
    float Sm = 0.f, S2 = 0.f;
    for (int w = 0; w < 8; w++){ Sm += red[tid*16 + w]; S2 += red[tid*16 + 8 + w]; }
    const float NV = (float)(O*64);
    float mean = Sm / NV;
    float var  = fmaxf(S2/NV - mean*mean, 0.f) * (NV/(NV-1.f));  // torch.std ddof=1
    float sc   = 1.f / (sqrtf(var) + 1e-5f);
    res[tid*2 + 0] = mean; res[tid*2 + 1] = sc;
  }
  __syncthreads();

#pragma unroll
  for (int s = 0; s < S; s++){
    const float mean = res[s*2 + 0], sc = res[s*2 + 1];
    if constexpr (LAST) {
#pragma unroll
      for (int r = 0; r < RT; r++)
#pragma unroll
        for (int ct = 0; ct < 4; ct++)
#pragma unroll
          for (int i = 0; i < 4; i++){
            int o = (wave + 8*r)*16 + kg*4 + i;
            int n = ct*16 + lrow;
            Outf[(size_t)(b0 + s)*(O*64) + o*64 + n] = lrelu((acc[r][ct][s][i] - mean)*sc);
          }
    } else {
#pragma unroll
      for (int r = 0; r < RT; r++)
#pragma unroll
        for (int ct = 0; ct < 4; ct++){
          int o0 = (wave + 8*r)*16 + kg*4;
          int n  = ct*16 + lrow;
          u16x4 pk;
#pragma unroll
          for (int i = 0; i < 4; i++) pk[i] = f2b(lrelu((acc[r][ct][s][i] - mean)*sc));
          *(u16x4*)(Xout + (size_t)(b0 + s)*outStride + (size_t)n*O + o0) = pk;
        }
    }
  }
}

// ---------------------------------------------------------------------------
extern "C" void kernel_launch(void* const* d_in, const int* in_sizes, int n_in,
                              void* d_out, int out_size, void* d_ws, size_t ws_size,
                              hipStream_t stream)
{
  // ALL float inputs are float32 (proven by R3's dtype-flag experiment).
  const float* trees = (const float*)d_in[0];
  const int*   gidx  = (const int*)d_in[1];
  const float* w1 = (const float*)d_in[2];
  const float* g1 = (const float*)d_in[4];  const float* be1 = (const float*)d_in[5];
  const float* w2 = (const float*)d_in[6];
  const float* g2 = (const float*)d_in[8];  const float* be2 = (const float*)d_in[9];
  const float* w3 = (const float*)d_in[10];
  const float* g3 = (const float*)d_in[12]; const float* be3 = (const float*)d_in[13];
  const float* w4 = (const float*)d_in[14];
  const float* g4 = (const float*)d_in[16]; const float* be4 = (const float*)d_in[17];
  const float* cw1 = (const float*)d_in[18]; const float* cb1 = (const float*)d_in[19];
  const float* cw2 = (const float*)d_in[20]; const float* cb2 = (const float*)d_in[21];
  const float* cw3 = (const float*)d_in[22]; const float* cb3 = (const float*)d_in[23];
  // linear biases b1..b4 cancel under training-mode BN — unused.

  // ws (~33.3 MiB): repacked conv weights + BN scratch + Xc2.
  // Wr3 MUST be in ws (read by the final conv while d_out is being rewritten).
  // Xc2 MUST be in ws (conv2's slice-writes to d_out would race other blocks'
  // Xc2 reads if Xc2 lived in d_out).
  char* ws = (char*)d_ws;
  size_t off = 0;
  auto alloc = [&](size_t bytes)->char*{ char* p = ws + off; off += (bytes + 255) & ~(size_t)255; return p; };
  u16*   Wr1  = (u16*)  alloc(128*192*2);
  u16*   Wr2  = (u16*)  alloc(256*384*2);
  u16*   Wr3  = (u16*)  alloc(512*768*2);
  float* partA= (float*)alloc(2*(64+256+1024+4096)*4);  // all 4 layers, contiguous
  float* ss1  = (float*)alloc(2*64*4);
  float* ss2  = (float*)alloc(2*256*4);
  float* ss3  = (float*)alloc(2*1024*4);
  float* ss4  = (float*)alloc(2*4096*4);
  u16*   Xc2  = (u16*)  alloc((size_t)2048*64*128*2);   // 32 MiB
  float* part1 = partA;             // 128 floats
  float* part2 = part1 + 2*64;      // 512
  float* part3 = part2 + 2*256;     // 2048
  float* part4 = part3 + 2*1024;    // 8192

  // d_out is (2048,512,64) FLOAT32 = 256 MiB. Host MLP-phase scratch inside it;
  // everything here is dead before conv2/conv3 touch d_out.
  // Y ping-pong: Ya holds L1/L3 outputs, Yb holds L2/L4 (a layer reads the
  // previous layer's f32 output while writing its own).
  float* outF = (float*)d_out;
  u16*   ob   = (u16*)d_out;                 // u16-unit view for offsets
  float* Yb   = (float*)ob;                  // u16 [0, 16,777,216)   L2/L4 out (max 33.5 MB)
  float* Ya   = (float*)(ob + 16777216);     // [.., 20,971,520)      L1/L3 out (max 8.4 MB)
  u16*   Tb   = ob + 20971520;               // [.., 21,102,592)
  u16*   Wb1  = ob + 21102592;               // [.., 21,106,688)
  u16*   Wb2  = ob + 21106688;               // [.., 21,123,072)
  u16*   Wb3  = ob + 21123072;               // [.., 21,385,216)
  u16*   Wb4  = ob + 21385216;               // [.., 25,579,520)
  u16*   Xt1  = ob + 25579520;               // [.., 33,968,128) < 134,217,728 ✓
  // Xc3: per-sample, INSIDE sample b's own 65,536-u16 slice of d_out
  // (first 16,384 u16 of each slice). conv3 stages it fully to LDS before
  // overwriting the slice — race-free. Everything above (Yb/Ya/Tb/Wb/Xt1) is
  // dead by the time conv2 writes Xc3 (bn_apply4_t and conv1 have consumed).
  u16*   Xc3  = ob;                          // base 0, sample stride 65,536 u16

  // prologue: zero stats, convert f32->bf16 (5 segments), repack conv weights
  zero_buf<<<(10880+255)/256, 256, 0, stream>>>(partA, 10880);
  cvt5<<<(1152000+255)/256, 256, 0, stream>>>(trees, Tb, 32768,
                                              w1, Wb1, 1024,
                                              w2, Wb2, 4096,
                                              w3, Wb3, 65536,
                                              w4, Wb4, 1048576);
  repack3<<<(516096+255)/256, 256, 0, stream>>>(cw1, Wr1, cw2, Wr2, cw3, Wr3);

  // MLP: gemm(+stats) -> finalize -> gemm(+applyA,+stats) -> ...
  gemm_nt<64,64,4,1,1,4,false,true><<<dim3(32,1), 256, 0, stream>>>(Tb, nullptr, Wb1, Ya, nullptr, part1, 2048, 64, 64);
  bn_finalize<<<1, 256, 0, stream>>>(part1, g1, be1, ss1, 64, 2048);
  gemm_nt<64,64,4,1,1,4,true,true><<<dim3(32,4), 256, 0, stream>>>(nullptr, Ya, Wb2, Yb, ss1, part2, 2048, 256, 64);
  bn_finalize<<<1, 256, 0, stream>>>(part2, g2, be2, ss2, 256, 2048);
  gemm_nt<64,64,4,1,1,4,true,true><<<dim3(32,16), 256, 0, stream>>>(nullptr, Yb, Wb3, Ya, ss2, part3, 2048, 1024, 256);
  bn_finalize<<<4, 256, 0, stream>>>(part3, g3, be3, ss3, 1024, 2048);
  gemm_nt<128,128,2,2,4,4,true,true><<<dim3(16,32), 256, 0, stream>>>(nullptr, Ya, Wb4, Yb, ss3, part4, 2048, 4096, 1024);
  bn_finalize<<<16, 256, 0, stream>>>(part4, g4, be4, ss4, 4096, 2048);
  bn_apply4_t<<<2048, 256, 0, stream>>>(Yb, ss4, Xt1);

  // tree-conv stack (S samples per block: weight reuse across samples)
  // conv1: Xt1 (d_out) -> Xc2 (ws)
  conv_norm< 64,128,false,4><<< 512, 512, 0, stream>>>(Xt1, 4096, Wr1, cb1, gidx, Xc2, 8192, nullptr);
  // conv2: Xc2 (ws) -> Xc3 slices (d_out, sample-strided 65,536 u16)
  conv_norm<128,256,false,2><<<1024, 512, 0, stream>>>(Xc2, 8192, Wr2, cb2, gidx, Xc3, 65536, nullptr);
  // conv3: Xc3 slices (d_out, staged to LDS first) -> final f32 output (d_out)
  conv_norm<256,512,true ,2><<<1024, 512, 0, stream>>>(Xc3, 65536, Wr3, cb3, gidx, nullptr, 0, outF);
}

// Round 5
// 631.440 us; speedup vs baseline: 1.2967x; 1.0154x over previous
//
#include <hip/hip_runtime.h>

typedef unsigned short u16;
typedef unsigned int   u32;
typedef __attribute__((ext_vector_type(8))) short short8;
typedef __attribute__((ext_vector_type(4))) float f32x4;
typedef __attribute__((ext_vector_type(4))) u16  u16x4;

#define DI __device__ __forceinline__

DI float b2f(u16 v){ return __builtin_bit_cast(float, (u32)v << 16); }
DI u16 f2b(float f){ u32 u = __builtin_bit_cast(u32, f); return (u16)((u + 0x7fffu + ((u >> 16) & 1u)) >> 16); }
DI float lrelu(float v){ return v > 0.f ? v : 0.01f * v; }

// ---------------- zero BN-stat accumulators (re-run every replay) ----------
__global__ __launch_bounds__(256)
void zero_buf(float* __restrict__ p, int n)
{
  int i = blockIdx.x*256 + threadIdx.x;
  if (i < n) p[i] = 0.f;
}

// ---------------- merged f32 -> bf16 conversion (5 segments) ---------------
__global__ __launch_bounds__(256)
void cvt5(const float* __restrict__ a0, u16* __restrict__ o0, int n0,
          const float* __restrict__ a1, u16* __restrict__ o1, int n1,
          const float* __restrict__ a2, u16* __restrict__ o2, int n2,
          const float* __restrict__ a3, u16* __restrict__ o3, int n3,
          const float* __restrict__ a4, u16* __restrict__ o4, int n4)
{
  int i = blockIdx.x*256 + threadIdx.x;
  const float* in; u16* out; int loc = i;
  if      (loc < n0){ in = a0; out = o0; }
  else if ((loc -= n0) < n1){ in = a1; out = o1; }
  else if ((loc -= n1) < n2){ in = a2; out = o2; }
  else if ((loc -= n2) < n3){ in = a3; out = o3; }
  else if ((loc -= n3) < n4){ in = a4; out = o4; }
  else return;
  float4 v = ((const float4*)in)[loc];
  u16x4 o; o[0]=f2b(v.x); o[1]=f2b(v.y); o[2]=f2b(v.z); o[3]=f2b(v.w);
  *(u16x4*)(out + (size_t)loc*4) = o;
}

// ---------------- merged conv weight repack: wr[o][k*C+c] = w[o][c*3+k] ----
__global__ __launch_bounds__(256)
void repack3(const float* __restrict__ cw1, u16* __restrict__ Wr1,
             const float* __restrict__ cw2, u16* __restrict__ Wr2,
             const float* __restrict__ cw3, u16* __restrict__ Wr3)
{
  int e = blockIdx.x*256 + threadIdx.x;
  const float* w; u16* wr; int C, lgC; int loc = e;
  if      (loc < 24576){ w = cw1; wr = Wr1; C = 64;  lgC = 6; }
  else if ((loc -= 24576) < 98304){ w = cw2; wr = Wr2; C = 128; lgC = 7; }
  else if ((loc -= 98304) < 393216){ w = cw3; wr = Wr3; C = 256; lgC = 8; }
  else return;
  int R = 3*C;
  int o = loc / R; int r = loc - o*R;
  int k = r >> lgC; int c = r & (C-1);
  wr[loc] = f2b(w[(size_t)o*R + c*3 + k]);
}

// ---------------- GEMM (NT): Y[M,N] = A[M,K] * W[N,K]^T, f32 out -----------
// APPLYA: A comes as f32 (prev layer's pre-BN Y) + ssA [scale(K), shift(K)];
//         staging applies v*sc+sh, lrelu, bf16-cast (bit-identical to the old
//         separate bn_apply pass).
// STATS:  per-block column sums/sumsq of the f32 output are reduced in LDS
//         and atomicAdd'ed into part [sum(N), sumsq(N)] (zeroed per replay).
template<int BM, int BN, int WROWS, int WCOLS, int RT, int CT, bool APPLYA, bool STATS>
__global__ __launch_bounds__(WROWS*WCOLS*64)
void gemm_nt(const u16* __restrict__ A, const float* __restrict__ Af,
             const u16* __restrict__ W, float* __restrict__ Y,
             const float* __restrict__ ssA, float* __restrict__ part,
             int M, int N, int K)
{
  constexpr int NT  = WROWS*WCOLS*64;
  constexpr int ALD = (BM*4)/NT;
  constexpr int BLD = (BN*4)/NT;
  __shared__ __align__(16) u16 As[BM*32];
  __shared__ __align__(16) u16 Bs[BN*32];
  const int tid  = threadIdx.x;
  const int wave = tid >> 6, lane = tid & 63;
  const int wr = wave / WCOLS, wc = wave % WCOLS;
  const int lrow = lane & 15, kg = lane >> 4;
  const int m0 = blockIdx.x * BM, n0 = blockIdx.y * BN;
  f32x4 acc[RT][CT] = {};
  for (int k0 = 0; k0 < K; k0 += 32) {
    uint4 av[ALD], bv[BLD];
    if constexpr (APPLYA){
#pragma unroll
      for (int i = 0; i < ALD; i++){
        int x = tid + i*NT; int row = m0 + (x>>2); int c0 = k0 + (x&3)*8;
        const float* ap = Af + (size_t)row*K + c0;
        float4 f0 = *(const float4*)ap;
        float4 f1 = *(const float4*)(ap + 4);
        u32 p0 = (u32)f2b(lrelu(f0.x*ssA[c0+0] + ssA[K+c0+0]))
               | ((u32)f2b(lrelu(f0.y*ssA[c0+1] + ssA[K+c0+1])) << 16);
        u32 p1 = (u32)f2b(lrelu(f0.z*ssA[c0+2] + ssA[K+c0+2]))
               | ((u32)f2b(lrelu(f0.w*ssA[c0+3] + ssA[K+c0+3])) << 16);
        u32 p2 = (u32)f2b(lrelu(f1.x*ssA[c0+4] + ssA[K+c0+4]))
               | ((u32)f2b(lrelu(f1.y*ssA[c0+5] + ssA[K+c0+5])) << 16);
        u32 p3 = (u32)f2b(lrelu(f1.z*ssA[c0+6] + ssA[K+c0+6]))
               | ((u32)f2b(lrelu(f1.w*ssA[c0+7] + ssA[K+c0+7])) << 16);
        av[i] = uint4{p0, p1, p2, p3};
      }
    } else {
#pragma unroll
      for (int i = 0; i < ALD; i++){ int x = tid + i*NT; av[i] = *(const uint4*)(A + (size_t)(m0 + (x>>2))*K + k0 + (x&3)*8); }
    }
#pragma unroll
    for (int i = 0; i < BLD; i++){ int x = tid + i*NT; bv[i] = *(const uint4*)(W + (size_t)(n0 + (x>>2))*K + k0 + (x&3)*8); }
    __syncthreads();
#pragma unroll
    for (int i = 0; i < ALD; i++){ *(uint4*)(As + (tid + i*NT)*8) = av[i]; }
#pragma unroll
    for (int i = 0; i < BLD; i++){ *(uint4*)(Bs + (tid + i*NT)*8) = bv[i]; }
    __syncthreads();
    short8 af[RT], bfr[CT];
#pragma unroll
    for (int r = 0; r < RT; r++) af[r]  = *(const short8*)(As + ((wr*RT + r)*16 + lrow)*32 + kg*8);
#pragma unroll
    for (int c = 0; c < CT; c++) bfr[c] = *(const short8*)(Bs + ((wc*CT + c)*16 + lrow)*32 + kg*8);
#pragma unroll
    for (int r = 0; r < RT; r++)
#pragma unroll
      for (int c = 0; c < CT; c++)
        acc[r][c] = __builtin_amdgcn_mfma_f32_16x16x32_bf16(af[r], bfr[c], acc[r][c], 0, 0, 0);
  }
  // C/D: col=lane&15, row=(lane>>4)*4+i  [m89/m91]
#pragma unroll
  for (int r = 0; r < RT; r++)
#pragma unroll
    for (int c = 0; c < CT; c++)
#pragma unroll
      for (int i = 0; i < 4; i++){
        int m = m0 + (wr*RT + r)*16 + kg*4 + i;
        int n = n0 + (wc*CT + c)*16 + lrow;
        Y[(size_t)m*N + n] = acc[r][c][i];
      }

  if constexpr (STATS){
    __shared__ float cs[BN], cs2[BN];
    for (int t = tid; t < BN; t += NT){ cs[t] = 0.f; cs2[t] = 0.f; }
    __syncthreads();
#pragma unroll
    for (int c = 0; c < CT; c++){
      float ls = 0.f, ls2 = 0.f;
#pragma unroll
      for (int r = 0; r < RT; r++)
#pragma unroll
        for (int i = 0; i < 4; i++){ float v = acc[r][c][i]; ls += v; ls2 += v*v; }
      ls  += __shfl_down(ls, 32);  ls  += __shfl_down(ls, 16);
      ls2 += __shfl_down(ls2, 32); ls2 += __shfl_down(ls2, 16);
      if (lane < 16){
        atomicAdd(&cs [(wc*CT + c)*16 + lrow], ls);
        atomicAdd(&cs2[(wc*CT + c)*16 + lrow], ls2);
      }
    }
    __syncthreads();
    for (int t = tid; t < BN; t += NT){
      atomicAdd(part + n0 + t,     cs[t]);
      atomicAdd(part + N + n0 + t, cs2[t]);
    }
  }
}

// ---------------- BN finalize: part row -> scale/shift ---------------------
__global__ __launch_bounds__(256)
void bn_finalize(const float* __restrict__ part, const float* __restrict__ g,
                 const float* __restrict__ be, float* __restrict__ ss, int N, int M)
{
  int n = blockIdx.x*256 + threadIdx.x;
  if (n >= N) return;
  float s = part[n], s2 = part[N + n];
  float inv  = 1.f / (float)M;
  float mean = s * inv;
  float var  = fmaxf(s2*inv - mean*mean, 0.f);
  float sc   = g[n] * rsqrtf(var + 1e-5f);
  ss[n]     = sc;
  ss[N + n] = be[n] - mean*sc;
}

// BN apply layer-4 + per-sample transpose: Xt[b][n][c] = lrelu(bn(h4))[b][c*64+n]
__global__ __launch_bounds__(256)
void bn_apply4_t(const float* __restrict__ Y, const float* __restrict__ ss, u16* __restrict__ Xt)
{
  const int b = blockIdx.x, tid = threadIdx.x;
  __shared__ u16 t[64*65];
  for (int j = tid; j < 4096; j += 256){
    float v = Y[(size_t)b*4096 + j];
    v = lrelu(v*ss[j] + ss[4096 + j]);
    int c = j >> 6, n = j & 63;
    t[c*65 + n] = f2b(v);
  }
  __syncthreads();
  for (int e = tid; e < 4096; e += 256){
    int n = e >> 6, c = e & 63;
    Xt[(size_t)b*4096 + n*64 + c] = t[c*65 + n];
  }
}

// ---------------- tree-conv + TreeLayerNorm + LeakyReLU --------------------
// S samples per block: weight fragments (global loads) are reused across S
// samples' MFMAs — weight traffic /S and S× MFMA work per load latency.
// Weight loads are software-pipelined 1-deep (afb double buffer): kb+32's
// loads issue before kb's MFMA cluster, hiding L2 latency under compute.
// Xin: per-sample base = Xin + b*inStride, node-major (64, C) bf16.
// non-LAST out: per-sample base = Xout + b*outStride, node-major (64, O) bf16.
// LAST: Outf + b*O*64, (O, 64) f32.
// Aliasing note: each block stages ALL its samples' inputs into LDS before
// writing any output, and touches only its own samples' slices.
template<int C, int O, bool LAST, int S>
__global__ __launch_bounds__(512)
void conv_norm(const u16* __restrict__ Xin, long inStride,
               const u16* __restrict__ Wr,
               const float* __restrict__ cb, const int* __restrict__ gidx,
               u16* __restrict__ Xout, long outStride, float* __restrict__ Outf)
{
  constexpr int R   = 3*C;
  constexpr int CSI = C + 8;
  constexpr int XS  = 65*CSI;          // per-sample LDS stride (u16)
  constexpr int RT  = O/128;
  constexpr int LGC = (C==64)?6:((C==128)?7:8);
  constexpr int CH8 = C/8;
  __shared__ __align__(16) u16 xs[S*XS];
  __shared__ int idxs[S*192];
  __shared__ float red[S*16];
  __shared__ float res[S*2];
  const int b0 = blockIdx.x * S, tid = threadIdx.x;
  const int wave = tid >> 6, lane = tid & 63;
  const int lrow = lane & 15, kg = lane >> 4;

#pragma unroll
  for (int s = 0; s < S; s++){
    const u16* xg = Xin + (size_t)(b0 + s)*inStride;
    u16* xd = xs + s*XS;
    for (int e = tid; e < 64*CH8; e += 512){
      int row = e / CH8, t = e % CH8;
      *(uint4*)(xd + row*CSI + t*8) = *(const uint4*)(xg + row*C + t*8);
    }
    if (tid < CH8){ uint4 z = {0,0,0,0}; *(uint4*)(xd + 64*CSI + tid*8) = z; }
    if (tid < 189) idxs[s*192 + tid] = gidx[(size_t)(b0 + s)*189 + tid] & 63;
  }
  __syncthreads();

  // packed tap indices: 7-bit fields (values 0..64), 1 VGPR per (s,ct)
  int jtp[S][4];
#pragma unroll
  for (int s = 0; s < S; s++)
#pragma unroll
    for (int ct = 0; ct < 4; ct++){
      int n = ct*16 + lrow;
      if (n == 0) jtp[s][ct] = 64 | (64<<7) | (64<<14);
      else        jtp[s][ct] = idxs[s*192 + 3*(n-1) + 0]
                             | (idxs[s*192 + 3*(n-1) + 1] << 7)
                             | (idxs[s*192 + 3*(n-1) + 2] << 14);
    }

  f32x4 acc[RT][4][S] = {};
  short8 afb[2][RT];
#pragma unroll
  for (int r = 0; r < RT; r++)
    afb[0][r] = *(const short8*)(Wr + (size_t)((wave + 8*r)*16 + lrow)*R + kg*8);
#pragma unroll
  for (int kb = 0; kb < R; kb += 32){
    const int cur = (kb >> 5) & 1;           // compile-time after unroll
    const int k   = kb >> LGC;               // wave-uniform tap 0..2
    const int c0  = (kb & (C-1)) + kg*8;
    if (kb + 32 < R){
#pragma unroll
      for (int r = 0; r < RT; r++)
        afb[cur^1][r] = *(const short8*)(Wr + (size_t)((wave + 8*r)*16 + lrow)*R + (kb + 32) + kg*8);
    }
#pragma unroll
    for (int s = 0; s < S; s++){
      short8 bfr[4];
#pragma unroll
      for (int ct = 0; ct < 4; ct++){
        int row = (jtp[s][ct] >> (7*k)) & 127;
        bfr[ct] = *(const short8*)(xs + s*XS + row*CSI + c0);
      }
#pragma unroll
      for (int r = 0; r < RT; r++)
#pragma unroll
        for (int ct = 0; ct < 4; ct++)
          acc[r][ct][s] = __builtin_amdgcn_mfma_f32_16x16x32_bf16(afb[cur][r], bfr[ct], acc[r][ct][s], 0, 0, 0);
    }
  }

  // bias (skip null column 0) + per-sample stats over (O x 64)
  float sv[S], sv2[S];
#pragma unroll
  for (int s = 0; s < S; s++){ sv[s] = 0.f; sv2[s] = 0.f; }
#pragma unroll
  for (int r = 0; r < RT; r++)
#pragma unroll
    for (int i = 0; i < 4; i++){
      int o = (wave + 8*r)*16 + kg*4 + i;
      float bias = cb[o];
#pragma unroll
      for (int ct = 0; ct < 4; ct++){
        int n = ct*16 + lrow;
#pragma unroll
        for (int s = 0; s < S; s++){
          float v = acc[r][ct][s][i];
          if (n != 0) v += bias;
          acc[r][ct][s][i] = v;
          sv[s] += v; sv2[s] += v*v;
        }
      }
    }
#pragma unroll
  for (int s = 0; s < S; s++){
#pragma unroll
    for (int off = 32; off > 0; off >>= 1){ sv[s] += __shfl_down(sv[s], off); sv2[s] += __shfl_down(sv2[s], off); }
    if (lane == 0){ red[s*16 + wave] = sv[s]; red[s*16 + 8 + wave] = sv2[s]; }
  }
  __syncthreads();
  if (tid < S){
    float Sm = 0.f, S2 = 0.f;
    for (int w = 0; w < 8; w++){ Sm += red[tid*16 + w]; S2 += red[tid*16 + 8 + w]; }
    const float NV = (float)(O*64);
    float mean = Sm / NV;
    float var  = fmaxf(S2/NV - mean*mean, 0.f) * (NV/(NV-1.f));  // torch.std ddof=1
    float sc   = 1.f / (sqrtf(var) + 1e-5f);
    res[tid*2 + 0] = mean; res[tid*2 + 1] = sc;
  }
  __syncthreads();

#pragma unroll
  for (int s = 0; s < S; s++){
    const float mean = res[s*2 + 0], sc = res[s*2 + 1];
    if constexpr (LAST) {
#pragma unroll
      for (int r = 0; r < RT; r++)
#pragma unroll
        for (int ct = 0; ct < 4; ct++)
#pragma unroll
          for (int i = 0; i < 4; i++){
            int o = (wave + 8*r)*16 + kg*4 + i;
            int n = ct*16 + lrow;
            Outf[(size_t)(b0 + s)*(O*64) + o*64 + n] = lrelu((acc[r][ct][s][i] - mean)*sc);
          }
    } else {
#pragma unroll
      for (int r = 0; r < RT; r++)
#pragma unroll
        for (int ct = 0; ct < 4; ct++){
          int o0 = (wave + 8*r)*16 + kg*4;
          int n  = ct*16 + lrow;
          u16x4 pk;
#pragma unroll
          for (int i = 0; i < 4; i++) pk[i] = f2b(lrelu((acc[r][ct][s][i] - mean)*sc));
          *(u16x4*)(Xout + (size_t)(b0 + s)*outStride + (size_t)n*O + o0) = pk;
        }
    }
  }
}

// ---------------------------------------------------------------------------
extern "C" void kernel_launch(void* const* d_in, const int* in_sizes, int n_in,
                              void* d_out, int out_size, void* d_ws, size_t ws_size,
                              hipStream_t stream)
{
  // ALL float inputs are float32 (proven by R3's dtype-flag experiment).
  const float* trees = (const float*)d_in[0];
  const int*   gidx  = (const int*)d_in[1];
  const float* w1 = (const float*)d_in[2];
  const float* g1 = (const float*)d_in[4];  const float* be1 = (const float*)d_in[5];
  const float* w2 = (const float*)d_in[6];
  const float* g2 = (const float*)d_in[8];  const float* be2 = (const float*)d_in[9];
  const float* w3 = (const float*)d_in[10];
  const float* g3 = (const float*)d_in[12]; const float* be3 = (const float*)d_in[13];
  const float* w4 = (const float*)d_in[14];
  const float* g4 = (const float*)d_in[16]; const float* be4 = (const float*)d_in[17];
  const float* cw1 = (const float*)d_in[18]; const float* cb1 = (const float*)d_in[19];
  const float* cw2 = (const float*)d_in[20]; const float* cb2 = (const float*)d_in[21];
  const float* cw3 = (const float*)d_in[22]; const float* cb3 = (const float*)d_in[23];
  // linear biases b1..b4 cancel under training-mode BN — unused.

  // ws (~33.3 MiB): repacked conv weights + BN scratch + Xc2.
  // Wr3 MUST be in ws (read by the final conv while d_out is being rewritten).
  // Xc2 MUST be in ws (conv2's slice-writes to d_out would race other blocks'
  // Xc2 reads if Xc2 lived in d_out).
  char* ws = (char*)d_ws;
  size_t off = 0;
  auto alloc = [&](size_t bytes)->char*{ char* p = ws + off; off += (bytes + 255) & ~(size_t)255; return p; };
  u16*   Wr1  = (u16*)  alloc(128*192*2);
  u16*   Wr2  = (u16*)  alloc(256*384*2);
  u16*   Wr3  = (u16*)  alloc(512*768*2);
  float* partA= (float*)alloc(2*(64+256+1024+4096)*4);  // all 4 layers, contiguous
  float* ss1  = (float*)alloc(2*64*4);
  float* ss2  = (float*)alloc(2*256*4);
  float* ss3  = (float*)alloc(2*1024*4);
  float* ss4  = (float*)alloc(2*4096*4);
  u16*   Xc2  = (u16*)  alloc((size_t)2048*64*128*2);   // 32 MiB
  float* part1 = partA;             // 128 floats
  float* part2 = part1 + 2*64;      // 512
  float* part3 = part2 + 2*256;     // 2048
  float* part4 = part3 + 2*1024;    // 8192

  // d_out is (2048,512,64) FLOAT32 = 256 MiB. Host MLP-phase scratch inside it;
  // everything here is dead before conv2/conv3 touch d_out.
  // Y ping-pong: Ya holds L1/L3 outputs, Yb holds L2/L4 (a layer reads the
  // previous layer's f32 output while writing its own).
  float* outF = (float*)d_out;
  u16*   ob   = (u16*)d_out;                 // u16-unit view for offsets
  float* Yb   = (float*)ob;                  // u16 [0, 16,777,216)   L2/L4 out (max 33.5 MB)
  float* Ya   = (float*)(ob + 16777216);     // [.., 20,971,520)      L1/L3 out (max 8.4 MB)
  u16*   Tb   = ob + 20971520;               // [.., 21,102,592)
  u16*   Wb1  = ob + 21102592;               // [.., 21,106,688)
  u16*   Wb2  = ob + 21106688;               // [.., 21,123,072)
  u16*   Wb3  = ob + 21123072;               // [.., 21,385,216)
  u16*   Wb4  = ob + 21385216;               // [.., 25,579,520)
  u16*   Xt1  = ob + 25579520;               // [.., 33,968,128) < 134,217,728 ✓
  // Xc3: per-sample, INSIDE sample b's own 65,536-u16 slice of d_out
  // (first 16,384 u16 of each slice). conv3 stages it fully to LDS before
  // overwriting the slice — race-free. Everything above (Yb/Ya/Tb/Wb/Xt1) is
  // dead by the time conv2 writes Xc3 (bn_apply4_t and conv1 have consumed).
  u16*   Xc3  = ob;                          // base 0, sample stride 65,536 u16

  // prologue: zero stats, convert f32->bf16 (5 segments), repack conv weights
  zero_buf<<<(10880+255)/256, 256, 0, stream>>>(partA, 10880);
  cvt5<<<(1152000+255)/256, 256, 0, stream>>>(trees, Tb, 32768,
                                              w1, Wb1, 1024,
                                              w2, Wb2, 4096,
                                              w3, Wb3, 65536,
                                              w4, Wb4, 1048576);
  repack3<<<(516096+255)/256, 256, 0, stream>>>(cw1, Wr1, cw2, Wr2, cw3, Wr3);

  // MLP: gemm(+stats) -> finalize -> gemm(+applyA,+stats) -> ...
  gemm_nt<64,64,4,1,1,4,false,true><<<dim3(32,1), 256, 0, stream>>>(Tb, nullptr, Wb1, Ya, nullptr, part1, 2048, 64, 64);
  bn_finalize<<<1, 256, 0, stream>>>(part1, g1, be1, ss1, 64, 2048);
  gemm_nt<64,64,4,1,1,4,true,true><<<dim3(32,4), 256, 0, stream>>>(nullptr, Ya, Wb2, Yb, ss1, part2, 2048, 256, 64);
  bn_finalize<<<1, 256, 0, stream>>>(part2, g2, be2, ss2, 256, 2048);
  gemm_nt<64,64,4,1,1,4,true,true><<<dim3(32,16), 256, 0, stream>>>(nullptr, Yb, Wb3, Ya, ss2, part3, 2048, 1024, 256);
  bn_finalize<<<4, 256, 0, stream>>>(part3, g3, be3, ss3, 1024, 2048);
  gemm_nt<128,128,2,2,4,4,true,true><<<dim3(16,32), 256, 0, stream>>>(nullptr, Ya, Wb4, Yb, ss3, part4, 2048, 4096, 1024);
  bn_finalize<<<16, 256, 0, stream>>>(part4, g4, be4, ss4, 4096, 2048);
  bn_apply4_t<<<2048, 256, 0, stream>>>(Yb, ss4, Xt1);

  // tree-conv stack (S samples per block: weight reuse across samples)
  // conv1: Xt1 (d_out) -> Xc2 (ws)
  conv_norm< 64,128,false,4><<< 512, 512, 0, stream>>>(Xt1, 4096, Wr1, cb1, gidx, Xc2, 8192, nullptr);
  // conv2: Xc2 (ws) -> Xc3 slices (d_out, sample-strided 65,536 u16)
  conv_norm<128,256,false,4><<< 512, 512, 0, stream>>>(Xc2, 8192, Wr2, cb2, gidx, Xc3, 65536, nullptr);
  // conv3: Xc3 slices (d_out, staged to LDS first) -> final f32 output (d_out)
  conv_norm<256,512,true ,2><<<1024, 512, 0, stream>>>(Xc3, 65536, Wr3, cb3, gidx, nullptr, 0, outF);
}